// Round 4
// baseline (268.764 us; speedup 1.0000x reference)
//
#include <hip/hip_runtime.h>
#include <math.h>

#define EPSV 1e-8f
#define QDIM 4096
#define LTOK 1024
#define PPAR 48

// XOR swizzle to spread pair accesses across LDS banks.
// Identity used throughout: phz(a ^ b) == phz(a) ^ swz(b)  (XOR-linear).
__device__ __forceinline__ int phz(int i) { return i ^ ((i >> 4) & 15); }
__device__ __forceinline__ int swz(int c) { return c ^ ((c >> 4) & 15); }

// ---------------- stage tables (ansatz 14, 12 qubits, 1 layer) --------------
// Bit position b = 11 - wire. Each stage owns 4 index bits (ascending);
// r-bit j of a thread's 16 register amps maps to canonical bit SB[S][j].
// Schedule re-verified (rounds 2 & 3): every pair of gates sharing a wire
// keeps reference order; params 0..47 each appear exactly once.
__device__ constexpr int SB[8][4] = {
  {0, 1, 2, 11},   // S0: wires 11,10,9,0   gates p0,p9,p10,p11 | p12,p13,p14
  {2, 3, 4, 5},    // S1: wires 9,8,7,6     p6,p7,p8 | p15,p16,p17
  {5, 6, 7, 8},    // S2: wires 6,5,4,3     p3,p4,p5 | p18,p19,p20
  {8, 9, 10, 11},  // S3: wires 3,2,1,0     p1,p2 | p21,p22,p23
  {0, 1, 10, 11},  // S4: wires 11,10,1,0   p24,p25,p34,p35 | p36,p37,p38
  {7, 8, 9, 10},   // S5: wires 4,3,2,1     p26,p27,p28 | p39,p40,p41
  {4, 5, 6, 7},    // S6: wires 7,6,5,4     p29,p30,p31 | p42,p43,p44
  {1, 2, 3, 4}};   // S7: wires 10,9,8,7    p32,p33 | p45,p46,p47
__device__ constexpr int SNG[8] = {7, 6, 6, 5, 7, 6, 6, 5};
// {type(0=RY,1=CRX), ja(RY tgt / CRX ctrl, local bit), jb(CRX tgt), param}
__device__ constexpr int SG[8][7][4] = {
  {{0,3,0,0},{0,2,0,9},{0,1,0,10},{0,0,0,11},{1,0,3,12},{1,1,0,13},{1,2,1,14}},
  {{0,3,0,6},{0,2,0,7},{0,1,0,8},{1,1,0,15},{1,2,1,16},{1,3,2,17},{0,0,0,0}},
  {{0,3,0,3},{0,2,0,4},{0,1,0,5},{1,1,0,18},{1,2,1,19},{1,3,2,20},{0,0,0,0}},
  {{0,2,0,1},{0,1,0,2},{1,1,0,21},{1,2,1,22},{1,3,2,23},{0,0,0,0},{0,0,0,0}},
  {{0,3,0,24},{0,2,0,25},{0,1,0,34},{0,0,0,35},{1,0,1,36},{1,3,0,37},{1,2,3,38}},
  {{0,2,0,26},{0,1,0,27},{0,0,0,28},{1,2,3,39},{1,1,2,40},{1,0,1,41},{0,0,0,0}},
  {{0,2,0,29},{0,1,0,30},{0,0,0,31},{1,2,3,42},{1,1,2,43},{1,0,1,44},{0,0,0,0}},
  {{0,2,0,32},{0,1,0,33},{1,2,3,45},{1,1,2,46},{1,0,1,47},{0,0,0,0},{0,0,0,0}}};

// Insert zeros at the 4 local bit positions (ascending): tid's 8 bits fill the rest.
template <int S>
__device__ __forceinline__ int i0_expand(int tid) {
  int i = tid;
#pragma unroll
  for (int j = 0; j < 4; ++j) {
    const int p = SB[S][j];
    i = ((i & ~((1 << p) - 1)) << 1) | (i & ((1 << p) - 1));
  }
  return i;
}

// OR-mask placing r's 4 bits at the stage's bit positions (folds to literal).
__device__ __forceinline__ int mof(int s, int r) {
  return ((r & 1) << SB[s][0]) | (((r >> 1) & 1) << SB[s][1]) |
         (((r >> 2) & 1) << SB[s][2]) | (((r >> 3) & 1) << SB[s][3]);
}

template <int S>
__device__ __forceinline__ void lds_gather(const float2* st, int tid, float2 (&amp)[16]) {
  const int pz = phz(i0_expand<S>(tid));
#pragma unroll
  for (int r = 0; r < 16; ++r) amp[r] = st[pz ^ swz(mof(S, r))];
}

template <int S>
__device__ __forceinline__ void lds_scatter(float2* st, int tid, const float2 (&amp)[16]) {
  const int pz = phz(i0_expand<S>(tid));
#pragma unroll
  for (int r = 0; r < 16; ++r) st[pz ^ swz(mof(S, r))] = amp[r];
}

// Apply the stage's gates on 16 register amps. All indices compile-time.
template <int S>
__device__ __forceinline__ void apply_stage(float2 (&amp)[16], const float2* prm) {
#pragma unroll
  for (int g = 0; g < SNG[S]; ++g) {
    const int ty = SG[S][g][0], ja = SG[S][g][1], jb = SG[S][g][2], pi = SG[S][g][3];
    const float2 w = prm[pi];
    const float cs = w.x, sn = w.y;
    if (ty == 0) {  // RY on local bit ja: a0' = c a0 - s a1 ; a1' = s a0 + c a1
#pragma unroll
      for (int r = 0; r < 16; ++r) {
        if (((r >> ja) & 1) == 0) {
          const int q = r | (1 << ja);
          const float2 a0 = amp[r], a1 = amp[q];
          amp[r] = make_float2(cs * a0.x - sn * a1.x, cs * a0.y - sn * a1.y);
          amp[q] = make_float2(sn * a0.x + cs * a1.x, sn * a0.y + cs * a1.y);
        }
      }
    } else {  // CRX (ctrl=ja bit ==1): a0' = c a0 - i s a1 ; a1' = -i s a0 + c a1
#pragma unroll
      for (int r = 0; r < 16; ++r) {
        if ((((r >> ja) & 1) == 1) && (((r >> jb) & 1) == 0)) {
          const int q = r | (1 << jb);
          const float2 a0 = amp[r], a1 = amp[q];
          amp[r] = make_float2(fmaf(cs, a0.x,  sn * a1.y), fmaf(cs, a0.y, -sn * a1.x));
          amp[q] = make_float2(fmaf(cs, a1.x,  sn * a0.y), fmaf(cs, a1.y, -sn * a0.x));
        }
      }
    }
  }
}

template <int S, bool SCAT>
__device__ __forceinline__ void do_stage(float2* st, int tid, float2 (&amp)[16],
                                         const float2* prm) {
  __syncthreads();  // previous scatter complete before re-partitioned gather
  lds_gather<S>(st, tid, amp);
  apply_stage<S>(amp, prm);
  if (SCAT) lds_scatter<S>(st, tid, amp);  // same thread-exclusive slots: no hazard
}

// 256-thread block sum reduction; result broadcast to all threads.
__device__ __forceinline__ float block_reduce_sum(float v, float* red, int tid) {
#pragma unroll
  for (int off = 32; off > 0; off >>= 1) v += __shfl_down(v, off, 64);
  __syncthreads();
  if ((tid & 63) == 0) red[tid >> 6] = v;
  __syncthreads();
  return red[0] + red[1] + red[2] + red[3];
}

// Batched 3-value block reduction (one barrier pair instead of three).
__device__ __forceinline__ float3 block_reduce3(float a, float b, float c,
                                                float* red, int tid) {
#pragma unroll
  for (int off = 32; off > 0; off >>= 1) {
    a += __shfl_down(a, off, 64);
    b += __shfl_down(b, off, 64);
    c += __shfl_down(c, off, 64);
  }
  __syncthreads();
  if ((tid & 63) == 0) {
    const int w = tid >> 6;
    red[w] = a; red[4 + w] = b; red[8 + w] = c;
  }
  __syncthreads();
  return make_float3(red[0] + red[1] + red[2] + red[3],
                     red[4] + red[5] + red[6] + red[7],
                     red[8] + red[9] + red[10] + red[11]);
}

// ---- angles: cssn[t][g] = (cos(h), sin(h)), h = 0.5*(emb.W^T + b) ----------
__global__ __launch_bounds__(64) void k_angles(
    const float* __restrict__ emb, const float* __restrict__ W,
    const float* __restrict__ b, float2* __restrict__ cssn) {
  __shared__ float4 e4[128];
  const int tid = threadIdx.x, t = blockIdx.x;
  const float4* E4 = (const float4*)(emb + (size_t)t * 512);
  e4[tid * 2] = E4[tid * 2];
  e4[tid * 2 + 1] = E4[tid * 2 + 1];
  __syncthreads();
  if (tid < PPAR) {
    const float4* W4 = (const float4*)(W + (size_t)tid * 512);
    float a = 0.f;
#pragma unroll 4
    for (int k = 0; k < 128; ++k) {
      const float4 wv = W4[k], ev = e4[k];
      a += wv.x * ev.x + wv.y * ev.y + wv.z * ev.z + wv.w * ev.w;
    }
    const float h = 0.5f * (a + b[tid]);
    float sn, cs;
    sincosf(h, &sn, &cs);
    cssn[t * PPAR + tid] = make_float2(cs, sn);
  }
}

// ---- init: lcu norm, qsum, ff cos/sin, mono = basis0, acc = q0*basis0 ------
__global__ __launch_bounds__(256) void k_init(
    const float* __restrict__ lre, const float* __restrict__ lim,
    const float* __restrict__ qc, const float* __restrict__ ffp,
    float* __restrict__ scal, float2* __restrict__ ffcs,
    float2* __restrict__ mono, float2* __restrict__ acc) {
  __shared__ float red[4];
  const int tid = threadIdx.x;
  float s = 0.f;
#pragma unroll
  for (int j = 0; j < 4; ++j) {
    const int t = tid + 256 * j;
    s += sqrtf(lre[t] * lre[t] + lim[t] * lim[t]);
  }
  const float tot = block_reduce_sum(s, red, tid);
  if (tid == 0) {
    scal[0] = fmaxf(tot, EPSV);
    scal[1] = fmaxf(fabsf(qc[0]) + fabsf(qc[1]) + fabsf(qc[2]) + fabsf(qc[3]), EPSV);
  }
  if (tid < PPAR) {
    const float h = 0.5f * ffp[tid];
    float sn, cs;
    sincosf(h, &sn, &cs);
    ffcs[tid] = make_float2(cs, sn);
  }
  const float q0 = qc[0];
#pragma unroll
  for (int j = 0; j < 16; ++j) {
    const int d = tid + 256 * j;
    mono[d] = make_float2(d == 0 ? 1.f : 0.f, 0.f);
    acc[d]  = make_float2(d == 0 ? q0 : 0.f, 0.f);
  }
}

// Stage-0 gather from canonical global layout. mof(0,r) = r for r<8,
// = 2048 + (r-8) for r>=8  ->  two contiguous 64B runs per thread
// (i0 has bits 0..2 clear -> 64B aligned).
__device__ __forceinline__ float load16_g(const float2* __restrict__ src, int i0,
                                          float2 (&amp)[16]) {
  const float4* a4 = (const float4*)(src + i0);
  const float4* b4 = (const float4*)(src + i0 + 2048);
  float nr = 0.f;
#pragma unroll
  for (int j = 0; j < 4; ++j) {
    const float4 va = a4[j], vb = b4[j];
    amp[2 * j]     = make_float2(va.x, va.y);
    amp[2 * j + 1] = make_float2(va.z, va.w);
    amp[8 + 2 * j]     = make_float2(vb.x, vb.y);
    amp[8 + 2 * j + 1] = make_float2(vb.z, vb.w);
    nr += va.x * va.x + va.y * va.y + va.z * va.z + va.w * va.w;
    nr += vb.x * vb.x + vb.y * vb.y + vb.z * vb.z + vb.w * vb.w;
  }
  return nr;
}

// ---- evolve: TPB tokens/block; staged register simulation ------------------
template <int TPB>
__global__ __launch_bounds__(256, 4) void k_evolve(
    const float2* __restrict__ cssn, const float* __restrict__ lre,
    const float* __restrict__ lim, const float* __restrict__ scal,
    const float2* __restrict__ mono, float2* __restrict__ partial) {
  __shared__ float2 st[QDIM];
  __shared__ float2 prm[PPAR];
  __shared__ float red[4];
  const int tid = threadIdx.x;
  const float lnorm = scal[0];
  float2 racc[16];
  if (TPB > 1) {
#pragma unroll
    for (int r = 0; r < 16; ++r) racc[r] = make_float2(0.f, 0.f);
  }

  for (int ti = 0; ti < TPB; ++ti) {
    const int t = blockIdx.x * TPB + ti;
    __syncthreads();  // prm + st free (all waves past last token's reads)
    if (tid < PPAR) prm[tid] = cssn[(size_t)t * PPAR + tid];

    const int i0 = i0_expand<0>(tid);
    float2 amp[16];
    float nr = load16_g(mono, i0, amp);
    const float tot = block_reduce_sum(nr, red, tid);  // also fences prm writes
    if (tot < EPSV * EPSV) {  // ||mono|| < EPS -> evolve basis0 instead
#pragma unroll
      for (int r = 0; r < 16; ++r)
        amp[r] = make_float2((tid == 0 && r == 0) ? 1.f : 0.f, 0.f);
    }
    apply_stage<0>(amp, prm);
    lds_scatter<0>(st, tid, amp);
    do_stage<1, true>(st, tid, amp, prm);
    do_stage<2, true>(st, tid, amp, prm);
    do_stage<3, true>(st, tid, amp, prm);
    do_stage<4, true>(st, tid, amp, prm);
    do_stage<5, true>(st, tid, amp, prm);
    do_stage<6, true>(st, tid, amp, prm);
    do_stage<7, false>(st, tid, amp, prm);  // final stage stays in registers

    const float wr = lre[t] / lnorm, wi = lim[t] / lnorm;
    if (TPB == 1) {
      // direct weighted store: no racc registers needed
#pragma unroll
      for (int r = 0; r < 16; ++r)
        partial[(size_t)blockIdx.x * QDIM + r * 256 + tid] =
            make_float2(wr * amp[r].x - wi * amp[r].y, wr * amp[r].y + wi * amp[r].x);
    } else {
#pragma unroll
      for (int r = 0; r < 16; ++r) {
        racc[r].x += wr * amp[r].x - wi * amp[r].y;
        racc[r].y += wr * amp[r].y + wi * amp[r].x;
      }
    }
  }
  if (TPB > 1) {
#pragma unroll
    for (int r = 0; r < 16; ++r)
      partial[(size_t)blockIdx.x * QDIM + r * 256 + tid] = racc[r];
  }
}

// ---- reduce stage 1: sum 16 consecutive block-partials (float4) -----------
__global__ __launch_bounds__(256) void k_fold(
    const float4* __restrict__ partial4, float4* __restrict__ partial24) {
  const int d = blockIdx.x * 256 + threadIdx.x;  // float4 index in [0, 2048)
  const int b0 = blockIdx.y * 16;
  float4 s = make_float4(0.f, 0.f, 0.f, 0.f);
#pragma unroll
  for (int b = 0; b < 16; ++b) {
    const float4 v = partial4[(size_t)(b0 + b) * 2048 + d];
    s.x += v.x; s.y += v.y; s.z += v.z; s.w += v.w;
  }
  partial24[(size_t)blockIdx.y * 2048 + d] = s;
}

// ---- reduce stage 2: un-permute stage-7 layout; mono = sum, acc += q*sum ---
__global__ __launch_bounds__(256) void k_update(
    const float4* __restrict__ partial24, int F, float4* __restrict__ mono4,
    float4* __restrict__ acc4, const float* __restrict__ qc, int k) {
  const int idx = blockIdx.x * 256 + threadIdx.x;  // float4 index in [0, 2048)
  float4 s = make_float4(0.f, 0.f, 0.f, 0.f);
  for (int f = 0; f < F; ++f) {
    const float4 v = partial24[(size_t)f * 2048 + idx];
    s.x += v.x; s.y += v.y; s.z += v.z; s.w += v.w;
  }
  // position pair p = 2*idx, 2*idx+1 (stage-7 layout: p = r*256 + t).
  // canonical i(p) = (t&1) | ((t&254)<<4) | (r<<1); for even t this is even and
  // i(p+1) = i(p)+1  ->  one float4 covers both.
  const int p = idx * 2;
  const int t = p & 255, r = p >> 8;
  const int i = ((t & 254) << 4) | (r << 1);  // (t&1)==0
  mono4[i >> 1] = s;
  const float q = qc[k];
  float4 a = acc4[i >> 1];
  a.x += q * s.x; a.y += q * s.y; a.z += q * s.z; a.w += q * s.w;
  acc4[i >> 1] = a;
}

// ---- final: normalize acc, staged ff ansatz, measure X/Y/Z -----------------
__global__ __launch_bounds__(256) void k_final(
    const float2* __restrict__ acc, const float* __restrict__ scal,
    const float2* __restrict__ ffcs, float* __restrict__ out) {
  __shared__ float2 st[QDIM];
  __shared__ float2 prm[PPAR];
  __shared__ float red[12];
  const int tid = threadIdx.x;
  if (tid < PPAR) prm[tid] = ffcs[tid];

  const int i0 = i0_expand<0>(tid);
  float2 amp[16];
  float nr = load16_g(acc, i0, amp);
  const float na = sqrtf(block_reduce_sum(nr, red, tid));  // fences prm
  const float qsum = scal[1];
  const bool small = na < EPSV * qsum;  // ||acc/qsum|| < EPS
  const float inv = small ? 0.f : 1.f / na;
#pragma unroll
  for (int r = 0; r < 16; ++r) {
    if (small) amp[r] = make_float2((tid == 0 && r == 0) ? 1.f : 0.f, 0.f);
    else { amp[r].x *= inv; amp[r].y *= inv; }
  }
  apply_stage<0>(amp, prm);
  lds_scatter<0>(st, tid, amp);
  do_stage<1, true>(st, tid, amp, prm);
  do_stage<2, true>(st, tid, amp, prm);
  do_stage<3, true>(st, tid, amp, prm);
  do_stage<4, true>(st, tid, amp, prm);
  do_stage<5, true>(st, tid, amp, prm);
  do_stage<6, true>(st, tid, amp, prm);
  do_stage<7, true>(st, tid, amp, prm);
  __syncthreads();

  for (int w = 0; w < 12; ++w) {
    const int bt = 11 - w;
    const int m = (1 << bt) - 1;
    const int dlt = swz(1 << bt);
    float xr = 0.f, xi = 0.f, zz = 0.f;
#pragma unroll
    for (int it = 0; it < 8; ++it) {
      const int pp = tid + it * 256;
      const int ia = ((pp & ~m) << 1) | (pp & m);
      const int p0 = phz(ia), p1 = p0 ^ dlt;
      const float2 a0 = st[p0], a1 = st[p1];
      xr += a0.x * a1.x + a0.y * a1.y;   // Re(conj(a0)*a1)
      xi += a0.x * a1.y - a0.y * a1.x;   // Im(conj(a0)*a1)
      zz += a0.x * a0.x + a0.y * a0.y - a1.x * a1.x - a1.y * a1.y;
    }
    const float3 s3 = block_reduce3(xr, xi, zz, red, tid);
    if (tid == 0) { out[w] = 2.f * s3.x; out[12 + w] = 2.f * s3.y; out[24 + w] = s3.z; }
  }
}

extern "C" void kernel_launch(void* const* d_in, const int* in_sizes, int n_in,
                              void* d_out, int out_size, void* d_ws, size_t ws_size,
                              hipStream_t stream) {
  const float* emb = (const float*)d_in[0];
  const float* W   = (const float*)d_in[1];
  const float* bb  = (const float*)d_in[2];
  const float* qc  = (const float*)d_in[3];
  const float* lre = (const float*)d_in[4];
  const float* lim = (const float*)d_in[5];
  const float* ffp = (const float*)d_in[6];
  float* out = (float*)d_out;

  char* ws = (char*)d_ws;
  size_t off = 0;
  float2* cssn = (float2*)(ws + off); off += (size_t)LTOK * PPAR * 8;  // 384 KB
  float* scal  = (float*)(ws + off);  off += 256;
  float2* ffcs = (float2*)(ws + off); off += 512;
  float2* mono = (float2*)(ws + off); off += (size_t)QDIM * 8;
  float2* acc  = (float2*)(ws + off); off += (size_t)QDIM * 8;
  const size_t base = off;

  auto need = [&](int NB) {
    return base + (size_t)NB * QDIM * 8 + (size_t)(NB / 16) * QDIM * 8;
  };
  // TPB ladder: keep >=2 blocks/CU whenever workspace allows.
  int TPB;
  if (ws_size >= need(1024)) TPB = 1;        // 1024 blocks, 4/CU, ~34.5 MB
  else if (ws_size >= need(512)) TPB = 2;    // 512 blocks, 2/CU, ~17.5 MB
  else if (ws_size >= need(256)) TPB = 4;    // 256 blocks, 1/CU, ~9 MB
  else TPB = 16;                             // 64 blocks, ~2.6 MB
  const int NB = LTOK / TPB, F = NB / 16;
  float2* partial  = (float2*)(ws + base);
  float2* partial2 = (float2*)(ws + base + (size_t)NB * QDIM * 8);

  k_init<<<1, 256, 0, stream>>>(lre, lim, qc, ffp, scal, ffcs, mono, acc);
  k_angles<<<LTOK, 64, 0, stream>>>(emb, W, bb, cssn);
  for (int k = 1; k <= 3; ++k) {
    if (TPB == 1)
      k_evolve<1><<<NB, 256, 0, stream>>>(cssn, lre, lim, scal, mono, partial);
    else if (TPB == 2)
      k_evolve<2><<<NB, 256, 0, stream>>>(cssn, lre, lim, scal, mono, partial);
    else if (TPB == 4)
      k_evolve<4><<<NB, 256, 0, stream>>>(cssn, lre, lim, scal, mono, partial);
    else
      k_evolve<16><<<NB, 256, 0, stream>>>(cssn, lre, lim, scal, mono, partial);
    k_fold<<<dim3(8, F), 256, 0, stream>>>((const float4*)partial, (float4*)partial2);
    k_update<<<8, 256, 0, stream>>>((const float4*)partial2, F, (float4*)mono,
                                    (float4*)acc, qc, k);
  }
  k_final<<<1, 256, 0, stream>>>(acc, scal, ffcs, out);
}

// Round 5
// 259.130 us; speedup vs baseline: 1.0372x; 1.0372x over previous
//
#include <hip/hip_runtime.h>
#include <math.h>

#define EPSV 1e-8f
#define QDIM 4096
#define LTOK 1024
#define PPAR 48

// XOR swizzle to spread pair accesses across LDS banks.
// Identity used throughout: phz(a ^ b) == phz(a) ^ swz(b)  (XOR-linear).
__device__ __forceinline__ int phz(int i) { return i ^ ((i >> 4) & 15); }
__device__ __forceinline__ int swz(int c) { return c ^ ((c >> 4) & 15); }

// ---------------- stage tables (ansatz 14, 12 qubits, 1 layer) --------------
// Bit position b = 11 - wire. Each stage owns 4 index bits (ascending);
// r-bit j of a thread's 16 register amps maps to canonical bit SB[S][j].
__device__ constexpr int SB[8][4] = {
  {0, 1, 2, 11},   // S0: wires 11,10,9,0   gates p0,p9,p10,p11 | p12,p13,p14
  {2, 3, 4, 5},    // S1: wires 9,8,7,6     p6,p7,p8 | p15,p16,p17
  {5, 6, 7, 8},    // S2: wires 6,5,4,3     p3,p4,p5 | p18,p19,p20
  {8, 9, 10, 11},  // S3: wires 3,2,1,0     p1,p2 | p21,p22,p23
  {0, 1, 10, 11},  // S4: wires 11,10,1,0   p24,p25,p34,p35 | p36,p37,p38
  {7, 8, 9, 10},   // S5: wires 4,3,2,1     p26,p27,p28 | p39,p40,p41
  {4, 5, 6, 7},    // S6: wires 7,6,5,4     p29,p30,p31 | p42,p43,p44
  {1, 2, 3, 4}};   // S7: wires 10,9,8,7    p32,p33 | p45,p46,p47
__device__ constexpr int SNG[8] = {7, 6, 6, 5, 7, 6, 6, 5};
// {type(0=RY,1=CRX), ja(RY tgt / CRX ctrl, local bit), jb(CRX tgt), param}
__device__ constexpr int SG[8][7][4] = {
  {{0,3,0,0},{0,2,0,9},{0,1,0,10},{0,0,0,11},{1,0,3,12},{1,1,0,13},{1,2,1,14}},
  {{0,3,0,6},{0,2,0,7},{0,1,0,8},{1,1,0,15},{1,2,1,16},{1,3,2,17},{0,0,0,0}},
  {{0,3,0,3},{0,2,0,4},{0,1,0,5},{1,1,0,18},{1,2,1,19},{1,3,2,20},{0,0,0,0}},
  {{0,2,0,1},{0,1,0,2},{1,1,0,21},{1,2,1,22},{1,3,2,23},{0,0,0,0},{0,0,0,0}},
  {{0,3,0,24},{0,2,0,25},{0,1,0,34},{0,0,0,35},{1,0,1,36},{1,3,0,37},{1,2,3,38}},
  {{0,2,0,26},{0,1,0,27},{0,0,0,28},{1,2,3,39},{1,1,2,40},{1,0,1,41},{0,0,0,0}},
  {{0,2,0,29},{0,1,0,30},{0,0,0,31},{1,2,3,42},{1,1,2,43},{1,0,1,44},{0,0,0,0}},
  {{0,2,0,32},{0,1,0,33},{1,2,3,45},{1,1,2,46},{1,0,1,47},{0,0,0,0},{0,0,0,0}}};

// Insert zeros at the 4 local bit positions (ascending): tid's 8 bits fill the rest.
template <int S>
__device__ __forceinline__ int i0_expand(int tid) {
  int i = tid;
#pragma unroll
  for (int j = 0; j < 4; ++j) {
    const int p = SB[S][j];
    i = ((i & ~((1 << p) - 1)) << 1) | (i & ((1 << p) - 1));
  }
  return i;
}

// OR-mask placing r's 4 bits at the stage's bit positions (folds to literal).
__device__ __forceinline__ int mof(int s, int r) {
  return ((r & 1) << SB[s][0]) | (((r >> 1) & 1) << SB[s][1]) |
         (((r >> 2) & 1) << SB[s][2]) | (((r >> 3) & 1) << SB[s][3]);
}

template <int S>
__device__ __forceinline__ void lds_gather(const float2* st, int tid, float2 (&amp)[16]) {
  const int pz = phz(i0_expand<S>(tid));
#pragma unroll
  for (int r = 0; r < 16; ++r) amp[r] = st[pz ^ swz(mof(S, r))];
}

template <int S>
__device__ __forceinline__ void lds_scatter(float2* st, int tid, const float2 (&amp)[16]) {
  const int pz = phz(i0_expand<S>(tid));
#pragma unroll
  for (int r = 0; r < 16; ++r) st[pz ^ swz(mof(S, r))] = amp[r];
}

// Apply the stage's gates on 16 register amps. All indices compile-time.
template <int S>
__device__ __forceinline__ void apply_stage(float2 (&amp)[16], const float2* prm) {
#pragma unroll
  for (int g = 0; g < SNG[S]; ++g) {
    const int ty = SG[S][g][0], ja = SG[S][g][1], jb = SG[S][g][2], pi = SG[S][g][3];
    const float2 w = prm[pi];
    const float cs = w.x, sn = w.y;
    if (ty == 0) {  // RY on local bit ja: a0' = c a0 - s a1 ; a1' = s a0 + c a1
#pragma unroll
      for (int r = 0; r < 16; ++r) {
        if (((r >> ja) & 1) == 0) {
          const int q = r | (1 << ja);
          const float2 a0 = amp[r], a1 = amp[q];
          amp[r] = make_float2(cs * a0.x - sn * a1.x, cs * a0.y - sn * a1.y);
          amp[q] = make_float2(sn * a0.x + cs * a1.x, sn * a0.y + cs * a1.y);
        }
      }
    } else {  // CRX (ctrl=ja bit ==1): a0' = c a0 - i s a1 ; a1' = -i s a0 + c a1
#pragma unroll
      for (int r = 0; r < 16; ++r) {
        if ((((r >> ja) & 1) == 1) && (((r >> jb) & 1) == 0)) {
          const int q = r | (1 << jb);
          const float2 a0 = amp[r], a1 = amp[q];
          amp[r] = make_float2(fmaf(cs, a0.x,  sn * a1.y), fmaf(cs, a0.y, -sn * a1.x));
          amp[q] = make_float2(fmaf(cs, a1.x,  sn * a0.y), fmaf(cs, a1.y, -sn * a0.x));
        }
      }
    }
  }
}

template <int S, bool SCAT>
__device__ __forceinline__ void do_stage(float2* st, int tid, float2 (&amp)[16],
                                         const float2* prm) {
  __syncthreads();  // previous scatter complete before re-partitioned gather
  lds_gather<S>(st, tid, amp);
  apply_stage<S>(amp, prm);
  if (SCAT) lds_scatter<S>(st, tid, amp);  // same thread-exclusive slots: no hazard
}

// 256-thread block sum reduction; result broadcast to all threads.
__device__ __forceinline__ float block_reduce_sum(float v, float* red, int tid) {
#pragma unroll
  for (int off = 32; off > 0; off >>= 1) v += __shfl_down(v, off, 64);
  __syncthreads();
  if ((tid & 63) == 0) red[tid >> 6] = v;
  __syncthreads();
  return red[0] + red[1] + red[2] + red[3];
}

// Batched 3-value block reduction (one barrier pair instead of three).
__device__ __forceinline__ float3 block_reduce3(float a, float b, float c,
                                                float* red, int tid) {
#pragma unroll
  for (int off = 32; off > 0; off >>= 1) {
    a += __shfl_down(a, off, 64);
    b += __shfl_down(b, off, 64);
    c += __shfl_down(c, off, 64);
  }
  __syncthreads();
  if ((tid & 63) == 0) {
    const int w = tid >> 6;
    red[w] = a; red[4 + w] = b; red[8 + w] = c;
  }
  __syncthreads();
  return make_float3(red[0] + red[1] + red[2] + red[3],
                     red[4] + red[5] + red[6] + red[7],
                     red[8] + red[9] + red[10] + red[11]);
}

// ---- angles: cssn[t][g] = (cos(h), sin(h)), h = 0.5*(emb.W^T + b) ----------
__global__ __launch_bounds__(64) void k_angles(
    const float* __restrict__ emb, const float* __restrict__ W,
    const float* __restrict__ b, float2* __restrict__ cssn) {
  __shared__ float4 e4[128];
  const int tid = threadIdx.x, t = blockIdx.x;
  const float4* E4 = (const float4*)(emb + (size_t)t * 512);
  e4[tid * 2] = E4[tid * 2];
  e4[tid * 2 + 1] = E4[tid * 2 + 1];
  __syncthreads();
  if (tid < PPAR) {
    const float4* W4 = (const float4*)(W + (size_t)tid * 512);
    float a = 0.f;
#pragma unroll 4
    for (int k = 0; k < 128; ++k) {
      const float4 wv = W4[k], ev = e4[k];
      a += wv.x * ev.x + wv.y * ev.y + wv.z * ev.z + wv.w * ev.w;
    }
    const float h = 0.5f * (a + b[tid]);
    float sn, cs;
    sincosf(h, &sn, &cs);
    cssn[t * PPAR + tid] = make_float2(cs, sn);
  }
}

// ---- init: lcu norm, qsum, ff cos/sin, mono = basis0, acc = q0*basis0 ------
// snrm[0..7]: per-update-block partial ||mono||^2; init so sum == 1 (basis0).
__global__ __launch_bounds__(256) void k_init(
    const float* __restrict__ lre, const float* __restrict__ lim,
    const float* __restrict__ qc, const float* __restrict__ ffp,
    float* __restrict__ scal, float* __restrict__ snrm,
    float2* __restrict__ ffcs, float2* __restrict__ mono,
    float2* __restrict__ acc) {
  __shared__ float red[4];
  const int tid = threadIdx.x;
  float s = 0.f;
#pragma unroll
  for (int j = 0; j < 4; ++j) {
    const int t = tid + 256 * j;
    s += sqrtf(lre[t] * lre[t] + lim[t] * lim[t]);
  }
  const float tot = block_reduce_sum(s, red, tid);
  if (tid == 0) {
    scal[0] = fmaxf(tot, EPSV);
    scal[1] = fmaxf(fabsf(qc[0]) + fabsf(qc[1]) + fabsf(qc[2]) + fabsf(qc[3]), EPSV);
  }
  if (tid < 8) snrm[tid] = (tid == 0) ? 1.f : 0.f;
  if (tid < PPAR) {
    const float h = 0.5f * ffp[tid];
    float sn, cs;
    sincosf(h, &sn, &cs);
    ffcs[tid] = make_float2(cs, sn);
  }
  const float q0 = qc[0];
#pragma unroll
  for (int j = 0; j < 16; ++j) {
    const int d = tid + 256 * j;
    mono[d] = make_float2(d == 0 ? 1.f : 0.f, 0.f);
    acc[d]  = make_float2(d == 0 ? q0 : 0.f, 0.f);
  }
}

// Stage-0 gather from canonical global layout. mof(0,r) = r for r<8,
// = 2048 + (r-8) for r>=8  ->  two contiguous 64B runs per thread
// (i0 has bits 0..2 clear -> 64B aligned).
__device__ __forceinline__ float load16_g(const float2* __restrict__ src, int i0,
                                          float2 (&amp)[16]) {
  const float4* a4 = (const float4*)(src + i0);
  const float4* b4 = (const float4*)(src + i0 + 2048);
  float nr = 0.f;
#pragma unroll
  for (int j = 0; j < 4; ++j) {
    const float4 va = a4[j], vb = b4[j];
    amp[2 * j]     = make_float2(va.x, va.y);
    amp[2 * j + 1] = make_float2(va.z, va.w);
    amp[8 + 2 * j]     = make_float2(vb.x, vb.y);
    amp[8 + 2 * j + 1] = make_float2(vb.z, vb.w);
    nr += va.x * va.x + va.y * va.y + va.z * va.z + va.w * va.w;
    nr += vb.x * vb.x + vb.y * vb.y + vb.z * vb.z + vb.w * vb.w;
  }
  return nr;
}

// ---- evolve: TPB tokens/block; staged register simulation ------------------
// ||mono|| check uses precomputed snrm (8 partials) -> no per-token reduction.
template <int TPB>
__global__ __launch_bounds__(256, 4) void k_evolve(
    const float2* __restrict__ cssn, const float* __restrict__ lre,
    const float* __restrict__ lim, const float* __restrict__ scal,
    const float* __restrict__ snrm, const float2* __restrict__ mono,
    float2* __restrict__ partial) {
  __shared__ float2 st[QDIM];
  __shared__ float2 prm[PPAR];
  const int tid = threadIdx.x;
  const float lnorm = scal[0];
  const float m2 = snrm[0] + snrm[1] + snrm[2] + snrm[3] +
                   snrm[4] + snrm[5] + snrm[6] + snrm[7];
  const bool small = m2 < EPSV * EPSV;  // ||mono|| < EPS -> evolve basis0
  float2 racc[16];
  if (TPB > 1) {
#pragma unroll
    for (int r = 0; r < 16; ++r) racc[r] = make_float2(0.f, 0.f);
  }

  const int i0 = i0_expand<0>(tid);
  for (int ti = 0; ti < TPB; ++ti) {
    const int t = blockIdx.x * TPB + ti;
    if (TPB > 1 && ti > 0) __syncthreads();  // st + prm free
    if (tid < PPAR) prm[tid] = cssn[(size_t)t * PPAR + tid];

    float2 amp[16];
    load16_g(mono, i0, amp);
    __syncthreads();  // prm visible to all waves
    if (small) {
#pragma unroll
      for (int r = 0; r < 16; ++r)
        amp[r] = make_float2((tid == 0 && r == 0) ? 1.f : 0.f, 0.f);
    }
    apply_stage<0>(amp, prm);
    lds_scatter<0>(st, tid, amp);
    do_stage<1, true>(st, tid, amp, prm);
    do_stage<2, true>(st, tid, amp, prm);
    do_stage<3, true>(st, tid, amp, prm);
    do_stage<4, true>(st, tid, amp, prm);
    do_stage<5, true>(st, tid, amp, prm);
    do_stage<6, true>(st, tid, amp, prm);
    do_stage<7, false>(st, tid, amp, prm);  // final stage stays in registers

    const float wr = lre[t] / lnorm, wi = lim[t] / lnorm;
    if (TPB == 1) {
#pragma unroll
      for (int r = 0; r < 16; ++r)
        partial[(size_t)blockIdx.x * QDIM + r * 256 + tid] =
            make_float2(wr * amp[r].x - wi * amp[r].y, wr * amp[r].y + wi * amp[r].x);
    } else {
#pragma unroll
      for (int r = 0; r < 16; ++r) {
        racc[r].x += wr * amp[r].x - wi * amp[r].y;
        racc[r].y += wr * amp[r].y + wi * amp[r].x;
      }
    }
  }
  if (TPB > 1) {
#pragma unroll
    for (int r = 0; r < 16; ++r)
      partial[(size_t)blockIdx.x * QDIM + r * 256 + tid] = racc[r];
  }
}

// ---- reduce stage 1: sum 16 consecutive block-partials (float4) -----------
__global__ __launch_bounds__(256) void k_fold(
    const float4* __restrict__ partial4, float4* __restrict__ partial24) {
  const int d = blockIdx.x * 256 + threadIdx.x;  // float4 index in [0, 2048)
  const int b0 = blockIdx.y * 16;
  float4 s = make_float4(0.f, 0.f, 0.f, 0.f);
#pragma unroll
  for (int b = 0; b < 16; ++b) {
    const float4 v = partial4[(size_t)(b0 + b) * 2048 + d];
    s.x += v.x; s.y += v.y; s.z += v.z; s.w += v.w;
  }
  partial24[(size_t)blockIdx.y * 2048 + d] = s;
}

// ---- reduce stage 2: un-permute stage-7 layout; mono = sum, acc += q*sum;
//      also emit per-block partial ||mono||^2 into snrm[blockIdx.x] ---------
__global__ __launch_bounds__(256) void k_update(
    const float4* __restrict__ partial24, int F, float4* __restrict__ mono4,
    float4* __restrict__ acc4, const float* __restrict__ qc, int k,
    float* __restrict__ snrm) {
  __shared__ float red[4];
  const int tid = threadIdx.x;
  const int idx = blockIdx.x * 256 + tid;  // float4 index in [0, 2048)
  float4 s = make_float4(0.f, 0.f, 0.f, 0.f);
  for (int f = 0; f < F; ++f) {
    const float4 v = partial24[(size_t)f * 2048 + idx];
    s.x += v.x; s.y += v.y; s.z += v.z; s.w += v.w;
  }
  // position pair p = 2*idx, 2*idx+1 (stage-7 layout: p = r*256 + t).
  // canonical i(p) = (t&1) | ((t&254)<<4) | (r<<1); even t -> even i, and
  // i(p+1) = i(p)+1  ->  one float4 covers both.
  const int p = idx * 2;
  const int t = p & 255, r = p >> 8;
  const int i = ((t & 254) << 4) | (r << 1);  // (t&1)==0
  mono4[i >> 1] = s;
  const float q = qc[k];
  float4 a = acc4[i >> 1];
  a.x += q * s.x; a.y += q * s.y; a.z += q * s.z; a.w += q * s.w;
  acc4[i >> 1] = a;
  // partial norm^2 of the new mono for the next evolve's small-check
  const float nr = s.x * s.x + s.y * s.y + s.z * s.z + s.w * s.w;
  const float bn = block_reduce_sum(nr, red, tid);
  if (tid == 0) snrm[blockIdx.x] = bn;
}

// ---- ff-evolve: normalize acc, staged ff ansatz, store state (p-layout) ----
__global__ __launch_bounds__(256) void k_ffevolve(
    const float2* __restrict__ acc, const float* __restrict__ scal,
    const float2* __restrict__ ffcs, float2* __restrict__ fstate) {
  __shared__ float2 st[QDIM];
  __shared__ float2 prm[PPAR];
  __shared__ float red[4];
  const int tid = threadIdx.x;
  if (tid < PPAR) prm[tid] = ffcs[tid];

  const int i0 = i0_expand<0>(tid);
  float2 amp[16];
  const float nr = load16_g(acc, i0, amp);
  const float na = sqrtf(block_reduce_sum(nr, red, tid));  // fences prm
  const float qsum = scal[1];
  const bool small = na < EPSV * qsum;  // ||acc/qsum|| < EPS
  const float inv = small ? 0.f : 1.f / na;
#pragma unroll
  for (int r = 0; r < 16; ++r) {
    if (small) amp[r] = make_float2((tid == 0 && r == 0) ? 1.f : 0.f, 0.f);
    else { amp[r].x *= inv; amp[r].y *= inv; }
  }
  apply_stage<0>(amp, prm);
  lds_scatter<0>(st, tid, amp);
  do_stage<1, true>(st, tid, amp, prm);
  do_stage<2, true>(st, tid, amp, prm);
  do_stage<3, true>(st, tid, amp, prm);
  do_stage<4, true>(st, tid, amp, prm);
  do_stage<5, true>(st, tid, amp, prm);
  do_stage<6, true>(st, tid, amp, prm);
  do_stage<7, false>(st, tid, amp, prm);  // stays in registers
  // store in stage-7 position layout p = r*256 + tid (coalesced)
#pragma unroll
  for (int r = 0; r < 16; ++r) fstate[r * 256 + tid] = amp[r];
}

// ---- measurement: one block per wire; fstate is in stage-7 p-layout --------
// canonical bits of p: bit0 = p0; bits1-4 = p8-11; bits5-11 = p1-7.
__global__ __launch_bounds__(256) void k_meas(
    const float2* __restrict__ fstate, float* __restrict__ out) {
  __shared__ float red[12];
  const int w = blockIdx.x;      // wire
  const int b = 11 - w;          // canonical bit
  const int pd = (b == 0) ? 1 : ((b <= 4) ? (256 << (b - 1)) : (1 << (b - 4)));
  const int m = pd - 1;
  const int tid = threadIdx.x;
  float xr = 0.f, xi = 0.f, zz = 0.f;
#pragma unroll
  for (int it = 0; it < 8; ++it) {
    const int q = tid + it * 256;                 // pair index in [0, 2048)
    const int p0 = ((q & ~m) << 1) | (q & m);
    const float2 a0 = fstate[p0], a1 = fstate[p0 | pd];
    xr += a0.x * a1.x + a0.y * a1.y;   // Re(conj(a0)*a1)
    xi += a0.x * a1.y - a0.y * a1.x;   // Im(conj(a0)*a1)
    zz += a0.x * a0.x + a0.y * a0.y - a1.x * a1.x - a1.y * a1.y;
  }
  const float3 s3 = block_reduce3(xr, xi, zz, red, tid);
  if (tid == 0) { out[w] = 2.f * s3.x; out[12 + w] = 2.f * s3.y; out[24 + w] = s3.z; }
}

extern "C" void kernel_launch(void* const* d_in, const int* in_sizes, int n_in,
                              void* d_out, int out_size, void* d_ws, size_t ws_size,
                              hipStream_t stream) {
  const float* emb = (const float*)d_in[0];
  const float* W   = (const float*)d_in[1];
  const float* bb  = (const float*)d_in[2];
  const float* qc  = (const float*)d_in[3];
  const float* lre = (const float*)d_in[4];
  const float* lim = (const float*)d_in[5];
  const float* ffp = (const float*)d_in[6];
  float* out = (float*)d_out;

  char* ws = (char*)d_ws;
  size_t off = 0;
  float2* cssn = (float2*)(ws + off); off += (size_t)LTOK * PPAR * 8;  // 384 KB
  float* scal  = (float*)(ws + off);  off += 256;
  float* snrm  = (float*)(ws + off);  off += 256;
  float2* ffcs = (float2*)(ws + off); off += 512;
  float2* mono = (float2*)(ws + off); off += (size_t)QDIM * 8;
  float2* acc  = (float2*)(ws + off); off += (size_t)QDIM * 8;
  float2* fstate = (float2*)(ws + off); off += (size_t)QDIM * 8;
  const size_t base = off;

  auto need = [&](int NB) {
    return base + (size_t)NB * QDIM * 8 + (size_t)(NB / 16) * QDIM * 8;
  };
  // TPB ladder: keep >=2 blocks/CU whenever workspace allows.
  int TPB;
  if (ws_size >= need(1024)) TPB = 1;        // 1024 blocks, 4/CU, ~34.6 MB
  else if (ws_size >= need(512)) TPB = 2;    // 512 blocks, 2/CU, ~17.6 MB
  else if (ws_size >= need(256)) TPB = 4;    // 256 blocks, 1/CU, ~9 MB
  else TPB = 16;                             // 64 blocks, ~2.7 MB
  const int NB = LTOK / TPB, F = NB / 16;
  float2* partial  = (float2*)(ws + base);
  float2* partial2 = (float2*)(ws + base + (size_t)NB * QDIM * 8);

  k_init<<<1, 256, 0, stream>>>(lre, lim, qc, ffp, scal, snrm, ffcs, mono, acc);
  k_angles<<<LTOK, 64, 0, stream>>>(emb, W, bb, cssn);
  for (int k = 1; k <= 3; ++k) {
    if (TPB == 1)
      k_evolve<1><<<NB, 256, 0, stream>>>(cssn, lre, lim, scal, snrm, mono, partial);
    else if (TPB == 2)
      k_evolve<2><<<NB, 256, 0, stream>>>(cssn, lre, lim, scal, snrm, mono, partial);
    else if (TPB == 4)
      k_evolve<4><<<NB, 256, 0, stream>>>(cssn, lre, lim, scal, snrm, mono, partial);
    else
      k_evolve<16><<<NB, 256, 0, stream>>>(cssn, lre, lim, scal, snrm, mono, partial);
    k_fold<<<dim3(8, F), 256, 0, stream>>>((const float4*)partial, (float4*)partial2);
    k_update<<<8, 256, 0, stream>>>((const float4*)partial2, F, (float4*)mono,
                                    (float4*)acc, qc, k, snrm);
  }
  k_ffevolve<<<1, 256, 0, stream>>>(acc, scal, ffcs, fstate);
  k_meas<<<12, 256, 0, stream>>>(fstate, out);
}

// Round 10
// 257.898 us; speedup vs baseline: 1.0421x; 1.0048x over previous
//
#include <hip/hip_runtime.h>
#include <math.h>

#define EPSV 1e-8f
#define QDIM 4096
#define LTOK 1024
#define PPAR 48

// XOR swizzle to spread pair accesses across LDS banks.
// Identity used throughout: phz(a ^ b) == phz(a) ^ swz(b)  (XOR-linear).
__device__ __forceinline__ int phz(int i) { return i ^ ((i >> 4) & 15); }
__device__ __forceinline__ int swz(int c) { return c ^ ((c >> 4) & 15); }

// ---------------- stage tables (ansatz 14, 12 qubits, 1 layer) --------------
__device__ constexpr int SB[8][4] = {
  {0, 1, 2, 11},   // S0: wires 11,10,9,0   gates p0,p9,p10,p11 | p12,p13,p14
  {2, 3, 4, 5},    // S1: wires 9,8,7,6     p6,p7,p8 | p15,p16,p17
  {5, 6, 7, 8},    // S2: wires 6,5,4,3     p3,p4,p5 | p18,p19,p20
  {8, 9, 10, 11},  // S3: wires 3,2,1,0     p1,p2 | p21,p22,p23
  {0, 1, 10, 11},  // S4: wires 11,10,1,0   p24,p25,p34,p35 | p36,p37,p38
  {7, 8, 9, 10},   // S5: wires 4,3,2,1     p26,p27,p28 | p39,p40,p41
  {4, 5, 6, 7},    // S6: wires 7,6,5,4     p29,p30,p31 | p42,p43,p44
  {1, 2, 3, 4}};   // S7: wires 10,9,8,7    p32,p33 | p45,p46,p47
__device__ constexpr int SNG[8] = {7, 6, 6, 5, 7, 6, 6, 5};
// {type(0=RY,1=CRX), ja(RY tgt / CRX ctrl, local bit), jb(CRX tgt), param}
__device__ constexpr int SG[8][7][4] = {
  {{0,3,0,0},{0,2,0,9},{0,1,0,10},{0,0,0,11},{1,0,3,12},{1,1,0,13},{1,2,1,14}},
  {{0,3,0,6},{0,2,0,7},{0,1,0,8},{1,1,0,15},{1,2,1,16},{1,3,2,17},{0,0,0,0}},
  {{0,3,0,3},{0,2,0,4},{0,1,0,5},{1,1,0,18},{1,2,1,19},{1,3,2,20},{0,0,0,0}},
  {{0,2,0,1},{0,1,0,2},{1,1,0,21},{1,2,1,22},{1,3,2,23},{0,0,0,0},{0,0,0,0}},
  {{0,3,0,24},{0,2,0,25},{0,1,0,34},{0,0,0,35},{1,0,1,36},{1,3,0,37},{1,2,3,38}},
  {{0,2,0,26},{0,1,0,27},{0,0,0,28},{1,2,3,39},{1,1,2,40},{1,0,1,41},{0,0,0,0}},
  {{0,2,0,29},{0,1,0,30},{0,0,0,31},{1,2,3,42},{1,1,2,43},{1,0,1,44},{0,0,0,0}},
  {{0,2,0,32},{0,1,0,33},{1,2,3,45},{1,1,2,46},{1,0,1,47},{0,0,0,0},{0,0,0,0}}};

template <int S>
__device__ __forceinline__ int i0_expand(int tid) {
  int i = tid;
#pragma unroll
  for (int j = 0; j < 4; ++j) {
    const int p = SB[S][j];
    i = ((i & ~((1 << p) - 1)) << 1) | (i & ((1 << p) - 1));
  }
  return i;
}

__device__ __forceinline__ int mof(int s, int r) {
  return ((r & 1) << SB[s][0]) | (((r >> 1) & 1) << SB[s][1]) |
         (((r >> 2) & 1) << SB[s][2]) | (((r >> 3) & 1) << SB[s][3]);
}

template <int S>
__device__ __forceinline__ void lds_gather(const float2* st, int tid, float2 (&amp)[16]) {
  const int pz = phz(i0_expand<S>(tid));
#pragma unroll
  for (int r = 0; r < 16; ++r) amp[r] = st[pz ^ swz(mof(S, r))];
}

template <int S>
__device__ __forceinline__ void lds_scatter(float2* st, int tid, const float2 (&amp)[16]) {
  const int pz = phz(i0_expand<S>(tid));
#pragma unroll
  for (int r = 0; r < 16; ++r) st[pz ^ swz(mof(S, r))] = amp[r];
}

template <int S>
__device__ __forceinline__ void apply_stage(float2 (&amp)[16], const float2* prm) {
#pragma unroll
  for (int g = 0; g < SNG[S]; ++g) {
    const int ty = SG[S][g][0], ja = SG[S][g][1], jb = SG[S][g][2], pi = SG[S][g][3];
    const float2 w = prm[pi];
    const float cs = w.x, sn = w.y;
    if (ty == 0) {  // RY on local bit ja
#pragma unroll
      for (int r = 0; r < 16; ++r) {
        if (((r >> ja) & 1) == 0) {
          const int q = r | (1 << ja);
          const float2 a0 = amp[r], a1 = amp[q];
          amp[r] = make_float2(cs * a0.x - sn * a1.x, cs * a0.y - sn * a1.y);
          amp[q] = make_float2(sn * a0.x + cs * a1.x, sn * a0.y + cs * a1.y);
        }
      }
    } else {  // CRX (ctrl bit ja == 1), RX on bit jb
#pragma unroll
      for (int r = 0; r < 16; ++r) {
        if ((((r >> ja) & 1) == 1) && (((r >> jb) & 1) == 0)) {
          const int q = r | (1 << jb);
          const float2 a0 = amp[r], a1 = amp[q];
          amp[r] = make_float2(fmaf(cs, a0.x,  sn * a1.y), fmaf(cs, a0.y, -sn * a1.x));
          amp[q] = make_float2(fmaf(cs, a1.x,  sn * a0.y), fmaf(cs, a1.y, -sn * a0.x));
        }
      }
    }
  }
}

template <int S, bool SCAT>
__device__ __forceinline__ void do_stage(float2* st, int tid, float2 (&amp)[16],
                                         const float2* prm) {
  __syncthreads();  // previous scatter complete before re-partitioned gather
  lds_gather<S>(st, tid, amp);
  apply_stage<S>(amp, prm);
  if (SCAT) lds_scatter<S>(st, tid, amp);  // thread-exclusive slots: no hazard
}

__device__ __forceinline__ float block_reduce_sum(float v, float* red, int tid) {
#pragma unroll
  for (int off = 32; off > 0; off >>= 1) v += __shfl_down(v, off, 64);
  __syncthreads();
  if ((tid & 63) == 0) red[tid >> 6] = v;
  __syncthreads();
  return red[0] + red[1] + red[2] + red[3];
}

__device__ __forceinline__ float2 block_reduce2(float a, float b, float* red, int tid) {
#pragma unroll
  for (int off = 32; off > 0; off >>= 1) {
    a += __shfl_down(a, off, 64);
    b += __shfl_down(b, off, 64);
  }
  __syncthreads();
  if ((tid & 63) == 0) {
    const int w = tid >> 6;
    red[w] = a; red[4 + w] = b;
  }
  __syncthreads();
  return make_float2(red[0] + red[1] + red[2] + red[3],
                     red[4] + red[5] + red[6] + red[7]);
}

__device__ __forceinline__ float3 block_reduce3(float a, float b, float c,
                                                float* red, int tid) {
#pragma unroll
  for (int off = 32; off > 0; off >>= 1) {
    a += __shfl_down(a, off, 64);
    b += __shfl_down(b, off, 64);
    c += __shfl_down(c, off, 64);
  }
  __syncthreads();
  if ((tid & 63) == 0) {
    const int w = tid >> 6;
    red[w] = a; red[4 + w] = b; red[8 + w] = c;
  }
  __syncthreads();
  return make_float3(red[0] + red[1] + red[2] + red[3],
                     red[4] + red[5] + red[6] + red[7],
                     red[8] + red[9] + red[10] + red[11]);
}

// ---- angles: cssn[t][g] = (cos(h), sin(h)), h = 0.5*(emb.W^T + b) ----------
__global__ __launch_bounds__(64) void k_angles(
    const float* __restrict__ emb, const float* __restrict__ W,
    const float* __restrict__ b, float2* __restrict__ cssn) {
  __shared__ float4 e4[128];
  const int tid = threadIdx.x, t = blockIdx.x;
  const float4* E4 = (const float4*)(emb + (size_t)t * 512);
  e4[tid * 2] = E4[tid * 2];
  e4[tid * 2 + 1] = E4[tid * 2 + 1];
  __syncthreads();
  if (tid < PPAR) {
    const float4* W4 = (const float4*)(W + (size_t)tid * 512);
    float a = 0.f;
#pragma unroll 4
    for (int k = 0; k < 128; ++k) {
      const float4 wv = W4[k], ev = e4[k];
      a += wv.x * ev.x + wv.y * ev.y + wv.z * ev.z + wv.w * ev.w;
    }
    const float h = 0.5f * (a + b[tid]);
    float sn, cs;
    sincosf(h, &sn, &cs);
    cssn[t * PPAR + tid] = make_float2(cs, sn);
  }
}

// ---- init: lcu norm, qsum, ff cos/sin, mono = basis0, acc = q0*basis0 ------
__global__ __launch_bounds__(256) void k_init(
    const float* __restrict__ lre, const float* __restrict__ lim,
    const float* __restrict__ qc, const float* __restrict__ ffp,
    float* __restrict__ scal, float* __restrict__ snrm,
    float2* __restrict__ ffcs, float2* __restrict__ mono,
    float2* __restrict__ acc) {
  __shared__ float red[4];
  const int tid = threadIdx.x;
  float s = 0.f;
#pragma unroll
  for (int j = 0; j < 4; ++j) {
    const int t = tid + 256 * j;
    s += sqrtf(lre[t] * lre[t] + lim[t] * lim[t]);
  }
  const float tot = block_reduce_sum(s, red, tid);
  if (tid == 0) {
    scal[0] = fmaxf(tot, EPSV);
    scal[1] = fmaxf(fabsf(qc[0]) + fabsf(qc[1]) + fabsf(qc[2]) + fabsf(qc[3]), EPSV);
  }
  if (tid < 8) snrm[tid] = (tid == 0) ? 1.f : 0.f;
  if (tid < PPAR) {
    const float h = 0.5f * ffp[tid];
    float sn, cs;
    sincosf(h, &sn, &cs);
    ffcs[tid] = make_float2(cs, sn);
  }
  const float q0 = qc[0];
#pragma unroll
  for (int j = 0; j < 16; ++j) {
    const int d = tid + 256 * j;
    mono[d] = make_float2(d == 0 ? 1.f : 0.f, 0.f);
    acc[d]  = make_float2(d == 0 ? q0 : 0.f, 0.f);
  }
}

// Stage-0 gather from canonical global layout (two 64B runs per thread).
__device__ __forceinline__ float load16_g(const float2* __restrict__ src, int i0,
                                          float2 (&amp)[16]) {
  const float4* a4 = (const float4*)(src + i0);
  const float4* b4 = (const float4*)(src + i0 + 2048);
  float nr = 0.f;
#pragma unroll
  for (int j = 0; j < 4; ++j) {
    const float4 va = a4[j], vb = b4[j];
    amp[2 * j]     = make_float2(va.x, va.y);
    amp[2 * j + 1] = make_float2(va.z, va.w);
    amp[8 + 2 * j]     = make_float2(vb.x, vb.y);
    amp[8 + 2 * j + 1] = make_float2(vb.z, vb.w);
    nr += va.x * va.x + va.y * va.y + va.z * va.z + va.w * va.w;
    nr += vb.x * vb.x + vb.y * vb.y + vb.z * vb.z + vb.w * vb.w;
  }
  return nr;
}

// ---- evolve: TPB tokens/block; staged register simulation ------------------
// ffmode==0: LCU tokens — input mono raw, out-weight lcu[t]/lnorm,
//            small-check ||mono||^2 < EPS^2 (snrm = mono partials).
// ffmode==1: ff pass (1 block) — input acc scaled by 1/||acc||, weight (1,0),
//            small-check ||acc|| < EPS*qsum (snrm arg = acc norm partials).
// Same kernel symbol as the LCU evolves -> tests the I-cache-warmth theory
// (round-5: separate k_ffevolve symbol cost 57us at VALUBusy=0.024%).
template <int TPB>
__global__ __launch_bounds__(256, 4) void k_evolve(
    const float2* __restrict__ cssn, const float* __restrict__ lre,
    const float* __restrict__ lim, const float* __restrict__ scal,
    const float* __restrict__ snrm, const float2* __restrict__ mono,
    float2* __restrict__ partial, int ffmode) {
  __shared__ float2 st[QDIM];
  __shared__ float2 prm[PPAR];
  const int tid = threadIdx.x;
  const float m2 = snrm[0] + snrm[1] + snrm[2] + snrm[3] +
                   snrm[4] + snrm[5] + snrm[6] + snrm[7];
  bool small;
  float s_in = 1.f, lnorm = 1.f;
  if (ffmode) {
    const float na = sqrtf(m2);
    small = na < EPSV * scal[1];          // ||acc|| < EPS * qsum
    s_in = small ? 1.f : 1.f / na;        // ff_in = acc/||acc||
  } else {
    small = m2 < EPSV * EPSV;             // ||mono|| < EPS
    lnorm = scal[0];
  }
  float2 racc[16];
  if (TPB > 1) {
#pragma unroll
    for (int r = 0; r < 16; ++r) racc[r] = make_float2(0.f, 0.f);
  }
  const int i0 = i0_expand<0>(tid);
#pragma unroll 1
  for (int ti = 0; ti < TPB; ++ti) {
    const int t = blockIdx.x * TPB + ti;
    float wr, wi;
    if (ffmode) { wr = 1.f; wi = 0.f; }
    else { wr = lre[t] / lnorm; wi = lim[t] / lnorm; }
    if (TPB > 1 && ti > 0) __syncthreads();  // st + prm free
    if (tid < PPAR) prm[tid] = cssn[(size_t)t * PPAR + tid];
    float2 amp[16];
    load16_g(mono, i0, amp);
    __syncthreads();  // prm visible to all waves
    if (small) {
#pragma unroll
      for (int r = 0; r < 16; ++r)
        amp[r] = make_float2((tid == 0 && r == 0) ? 1.f : 0.f, 0.f);
    } else if (ffmode) {
#pragma unroll
      for (int r = 0; r < 16; ++r) { amp[r].x *= s_in; amp[r].y *= s_in; }
    }
    apply_stage<0>(amp, prm);
    lds_scatter<0>(st, tid, amp);
    do_stage<1, true>(st, tid, amp, prm);
    do_stage<2, true>(st, tid, amp, prm);
    do_stage<3, true>(st, tid, amp, prm);
    do_stage<4, true>(st, tid, amp, prm);
    do_stage<5, true>(st, tid, amp, prm);
    do_stage<6, true>(st, tid, amp, prm);
    do_stage<7, false>(st, tid, amp, prm);  // final stage stays in registers
    if (TPB == 1) {
#pragma unroll
      for (int r = 0; r < 16; ++r)
        partial[(size_t)blockIdx.x * QDIM + r * 256 + tid] =
            make_float2(wr * amp[r].x - wi * amp[r].y, wr * amp[r].y + wi * amp[r].x);
    } else {
#pragma unroll
      for (int r = 0; r < 16; ++r) {
        racc[r].x += wr * amp[r].x - wi * amp[r].y;
        racc[r].y += wr * amp[r].y + wi * amp[r].x;
      }
    }
  }
  if (TPB > 1) {
#pragma unroll
    for (int r = 0; r < 16; ++r)
      partial[(size_t)blockIdx.x * QDIM + r * 256 + tid] = racc[r];
  }
}

// ---- reduce stage 1: sum 16 consecutive block-partials (float4) -----------
__global__ __launch_bounds__(256) void k_fold(
    const float4* __restrict__ partial4, float4* __restrict__ partial24) {
  const int d = blockIdx.x * 256 + threadIdx.x;  // float4 index in [0, 2048)
  const int b0 = blockIdx.y * 16;
  float4 s = make_float4(0.f, 0.f, 0.f, 0.f);
#pragma unroll
  for (int b = 0; b < 16; ++b) {
    const float4 v = partial4[(size_t)(b0 + b) * 2048 + d];
    s.x += v.x; s.y += v.y; s.z += v.z; s.w += v.w;
  }
  partial24[(size_t)blockIdx.y * 2048 + d] = s;
}

// ---- reduce stage 2: un-permute stage-7 layout; mono = sum, acc += q*sum;
//      emit partial ||mono||^2 -> snrm and partial ||acc||^2 -> snrm2 -------
__global__ __launch_bounds__(256) void k_update(
    const float4* __restrict__ partial24, int F, float4* __restrict__ mono4,
    float4* __restrict__ acc4, const float* __restrict__ qc, int k,
    float* __restrict__ snrm, float* __restrict__ snrm2) {
  __shared__ float red[8];
  const int tid = threadIdx.x;
  const int idx = blockIdx.x * 256 + tid;  // float4 index in [0, 2048)
  float4 s = make_float4(0.f, 0.f, 0.f, 0.f);
  for (int f = 0; f < F; ++f) {
    const float4 v = partial24[(size_t)f * 2048 + idx];
    s.x += v.x; s.y += v.y; s.z += v.z; s.w += v.w;
  }
  // stage-7 layout p = r*256 + t; canonical i(p) = (t&1)|((t&254)<<4)|(r<<1);
  // even t -> even i and i(p+1)=i(p)+1 -> one float4 covers both.
  const int p = idx * 2;
  const int t = p & 255, r = p >> 8;
  const int i = ((t & 254) << 4) | (r << 1);
  mono4[i >> 1] = s;
  const float q = qc[k];
  float4 a = acc4[i >> 1];
  a.x += q * s.x; a.y += q * s.y; a.z += q * s.z; a.w += q * s.w;
  acc4[i >> 1] = a;
  const float nr = s.x * s.x + s.y * s.y + s.z * s.z + s.w * s.w;
  const float nr2 = a.x * a.x + a.y * a.y + a.z * a.z + a.w * a.w;
  const float2 bn = block_reduce2(nr, nr2, red, tid);
  if (tid == 0) { snrm[blockIdx.x] = bn.x; snrm2[blockIdx.x] = bn.y; }
}

// ---- measurement: one block per wire; fstate is in stage-7 p-layout --------
// canonical bits of p: bit0 = p0; bits1-4 = p8-11; bits5-11 = p1-7.
__global__ __launch_bounds__(256) void k_meas(
    const float2* __restrict__ fstate, float* __restrict__ out) {
  __shared__ float red[12];
  const int w = blockIdx.x;      // wire
  const int b = 11 - w;          // canonical bit
  const int pd = (b == 0) ? 1 : ((b <= 4) ? (256 << (b - 1)) : (1 << (b - 4)));
  const int m = pd - 1;
  const int tid = threadIdx.x;
  float xr = 0.f, xi = 0.f, zz = 0.f;
#pragma unroll
  for (int it = 0; it < 8; ++it) {
    const int q = tid + it * 256;                 // pair index in [0, 2048)
    const int p0 = ((q & ~m) << 1) | (q & m);
    const float2 a0 = fstate[p0], a1 = fstate[p0 | pd];
    xr += a0.x * a1.x + a0.y * a1.y;   // Re(conj(a0)*a1)
    xi += a0.x * a1.y - a0.y * a1.x;   // Im(conj(a0)*a1)
    zz += a0.x * a0.x + a0.y * a0.y - a1.x * a1.x - a1.y * a1.y;
  }
  const float3 s3 = block_reduce3(xr, xi, zz, red, tid);
  if (tid == 0) { out[w] = 2.f * s3.x; out[12 + w] = 2.f * s3.y; out[24 + w] = s3.z; }
}

extern "C" void kernel_launch(void* const* d_in, const int* in_sizes, int n_in,
                              void* d_out, int out_size, void* d_ws, size_t ws_size,
                              hipStream_t stream) {
  const float* emb = (const float*)d_in[0];
  const float* W   = (const float*)d_in[1];
  const float* bb  = (const float*)d_in[2];
  const float* qc  = (const float*)d_in[3];
  const float* lre = (const float*)d_in[4];
  const float* lim = (const float*)d_in[5];
  const float* ffp = (const float*)d_in[6];
  float* out = (float*)d_out;

  char* ws = (char*)d_ws;
  size_t off = 0;
  float2* cssn = (float2*)(ws + off); off += (size_t)LTOK * PPAR * 8;  // 384 KB
  float* scal  = (float*)(ws + off);  off += 256;
  float* snrm  = (float*)(ws + off);  off += 256;
  float* snrm2 = (float*)(ws + off);  off += 256;
  float2* ffcs = (float2*)(ws + off); off += 512;
  float2* mono = (float2*)(ws + off); off += (size_t)QDIM * 8;
  float2* acc  = (float2*)(ws + off); off += (size_t)QDIM * 8;
  float2* fstate = (float2*)(ws + off); off += (size_t)QDIM * 8;
  const size_t base = off;

  auto need = [&](int NB) {
    return base + (size_t)NB * QDIM * 8 + (size_t)(NB / 16) * QDIM * 8;
  };
  // TPB ladder: keep >=2 blocks/CU whenever workspace allows.
  int TPB;
  if (ws_size >= need(1024)) TPB = 1;        // 1024 blocks, 4/CU, ~34.6 MB
  else if (ws_size >= need(512)) TPB = 2;    // 512 blocks, 2/CU, ~17.6 MB
  else if (ws_size >= need(256)) TPB = 4;    // 256 blocks, 1/CU, ~9 MB
  else TPB = 16;                             // 64 blocks, ~2.7 MB
  const int NB = LTOK / TPB, F = NB / 16;
  float2* partial  = (float2*)(ws + base);
  float2* partial2 = (float2*)(ws + base + (size_t)NB * QDIM * 8);

  k_init<<<1, 256, 0, stream>>>(lre, lim, qc, ffp, scal, snrm, ffcs, mono, acc);
  k_angles<<<LTOK, 64, 0, stream>>>(emb, W, bb, cssn);
  for (int k = 1; k <= 3; ++k) {
    if (TPB == 1)
      k_evolve<1><<<NB, 256, 0, stream>>>(cssn, lre, lim, scal, snrm, mono, partial, 0);
    else if (TPB == 2)
      k_evolve<2><<<NB, 256, 0, stream>>>(cssn, lre, lim, scal, snrm, mono, partial, 0);
    else if (TPB == 4)
      k_evolve<4><<<NB, 256, 0, stream>>>(cssn, lre, lim, scal, snrm, mono, partial, 0);
    else
      k_evolve<16><<<NB, 256, 0, stream>>>(cssn, lre, lim, scal, snrm, mono, partial, 0);
    k_fold<<<dim3(8, F), 256, 0, stream>>>((const float4*)partial, (float4*)partial2);
    k_update<<<8, 256, 0, stream>>>((const float4*)partial2, F, (float4*)mono,
                                    (float4*)acc, qc, k, snrm, snrm2);
  }
  // ff pass through the same k_evolve<1> symbol: input acc, params ffcs
  // (token 0), weight (1,0), output fstate in stage-7 p-layout.
  k_evolve<1><<<1, 256, 0, stream>>>(ffcs, lre, lim, scal, snrm2, acc, fstate, 1);
  k_meas<<<12, 256, 0, stream>>>(fstate, out);
}